// Round 1
// baseline (380.577 us; speedup 1.0000x reference)
//
#include <hip/hip_runtime.h>
#include <hip/hip_bf16.h>

// Problem constants (reference: B=128, S=4096, C=64)
#define BB 128
#define SS 4096
#define CC 64

#define TCH 32          // output positions per wave
#define ROWS 33         // TCH + 1 (overlap row for p_{t+1})
#define PST 72          // padded row stride in bf16 elems (144 B, 16B-aligned, breaks worst bank conflicts)

typedef __attribute__((ext_vector_type(8))) short short8;
typedef __attribute__((ext_vector_type(4))) float floatx4;

__global__ __launch_bounds__(256, 3) void pkl_kernel(
        const float* __restrict__ logits,
        const float* __restrict__ M,
        float* __restrict__ out) {
    // bf16 tiles, rows padded to 72 elems (144 B)
    __shared__ __hip_bfloat16 m_lds[CC * PST];           // M row-major [c][d] == B as N x K
    __shared__ __hip_bfloat16 p_lds[4][ROWS * PST];      // per-wave log-softmax rows
    __shared__ __hip_bfloat16 v_lds[4][ROWS * PST];      // per-wave V = P * M^T rows (rows 1..32 written)

    const int tid  = threadIdx.x;
    const int lane = tid & 63;
    const int w    = tid >> 6;
    const int quad = lane >> 4;     // 0..3
    const int nlo  = lane & 15;     // 0..15

    // ---- stage M -> bf16 LDS (coalesced: 16 passes of 256 consecutive floats) ----
    for (int j = 0; j < 16; ++j) {
        int idx = j * 256 + tid;            // 0..4095
        int c = idx >> 6, d = idx & 63;
        m_lds[c * PST + d] = __float2bfloat16(M[idx]);
    }
    __syncthreads();

    const int chunk = blockIdx.x * 4 + w;   // 16384 chunks total
    const int b  = chunk >> 7;              // 128 chunks per batch row
    const int s0 = (chunk & 127) * TCH;

    __hip_bfloat16* pw = p_lds[w];
    __hip_bfloat16* vw = v_lds[w];

    // ---- phase 1: log_softmax per position, lane = class ----
    for (int i = 0; i < ROWS; ++i) {
        int row = s0 + i; if (row > SS - 1) row = SS - 1;   // clamp (masked later)
        float x = logits[((size_t)b * SS + row) * CC + lane];
        float mx = x;
        #pragma unroll
        for (int o = 32; o > 0; o >>= 1) mx = fmaxf(mx, __shfl_xor(mx, o));
        float e = exp2f((x - mx) * 1.4426950408889634f);
        float sm = e;
        #pragma unroll
        for (int o = 32; o > 0; o >>= 1) sm += __shfl_xor(sm, o);
        float p = (x - mx) - log2f(sm) * 0.6931471805599453f;
        pw[i * PST + lane] = __float2bfloat16(p);
    }

    // ---- phase 2: V[t][c] = sum_d P[t][d] * M[c][d], rows t = 1..32, via MFMA ----
    // A-frag: A[m = lane&15][k = quad*8 + j] -> p row (1 + mt*16 + nlo), 8 contiguous bf16
    // B-frag: B[n = lane&15][k = quad*8 + j] -> M row (nt*16 + nlo),    8 contiguous bf16
    floatx4 acc[2][4];
    #pragma unroll
    for (int mt = 0; mt < 2; ++mt)
        #pragma unroll
        for (int nt = 0; nt < 4; ++nt)
            acc[mt][nt] = (floatx4){0.f, 0.f, 0.f, 0.f};

    #pragma unroll
    for (int kt = 0; kt < 2; ++kt) {
        const int koff = kt * 32 + quad * 8;
        short8 bfrag[4];
        #pragma unroll
        for (int nt = 0; nt < 4; ++nt)
            bfrag[nt] = *reinterpret_cast<const short8*>(
                reinterpret_cast<const short*>(m_lds) + (nt * 16 + nlo) * PST + koff);
        #pragma unroll
        for (int mt = 0; mt < 2; ++mt) {
            short8 afrag = *reinterpret_cast<const short8*>(
                reinterpret_cast<const short*>(pw) + (1 + mt * 16 + nlo) * PST + koff);
            #pragma unroll
            for (int nt = 0; nt < 4; ++nt)
                acc[mt][nt] = __builtin_amdgcn_mfma_f32_16x16x32_bf16(
                    afrag, bfrag[nt], acc[mt][nt], 0, 0, 0);
        }
    }

    // C/D layout: col = lane&15, row = quad*4 + reg  (m89/m91-verified)
    #pragma unroll
    for (int mt = 0; mt < 2; ++mt)
        #pragma unroll
        for (int nt = 0; nt < 4; ++nt)
            #pragma unroll
            for (int r = 0; r < 4; ++r) {
                int t = 1 + mt * 16 + quad * 4 + r;
                int c = nt * 16 + nlo;
                vw[t * PST + c] = __float2bfloat16(acc[mt][nt][r]);
            }

    // ---- phase 3: r[t] = dot(p_t, v_{t+1}), lane = class, shuffle-reduce ----
    const size_t outbase = (size_t)b * (SS - 1) + s0;
    for (int i = 0; i < TCH; ++i) {
        if (s0 + i > SS - 2) break;   // last valid t is S-2
        float pv = __bfloat162float(pw[i * PST + lane]);
        float vv = __bfloat162float(vw[(i + 1) * PST + lane]);
        float prod = pv * vv;
        #pragma unroll
        for (int o = 32; o > 0; o >>= 1) prod += __shfl_xor(prod, o);
        if (lane == 0) out[outbase + i] = prod;
    }
}

extern "C" void kernel_launch(void* const* d_in, const int* in_sizes, int n_in,
                              void* d_out, int out_size, void* d_ws, size_t ws_size,
                              hipStream_t stream) {
    const float* logits = (const float*)d_in[0];   // [128, 4096, 64] fp32
    const float* M      = (const float*)d_in[1];   // [64, 64] fp32
    float* out          = (float*)d_out;           // [128, 4095] fp32

    // 16384 wave-chunks / 4 waves per block
    dim3 grid(4096), block(256);
    hipLaunchKernelGGL(pkl_kernel, grid, block, 0, stream, logits, M, out);
}

// Round 2
// 196.177 us; speedup vs baseline: 1.9400x; 1.9400x over previous
//
#include <hip/hip_runtime.h>
#include <hip/hip_bf16.h>

// Problem: B=128, S=4096, C=64.  r[b,t] = p_t . (M p_{t+1}),  p = log_softmax(logits)
#define SS 4096
#define CC 64
#define PST 72           // padded LDS row stride in bf16 elems (144 B: 16B-aligned rows)
#define ROWS 129         // 128 positions per block + 1 overlap row

typedef __attribute__((ext_vector_type(8))) short short8;
typedef __attribute__((ext_vector_type(4))) float floatx4;

static __device__ __forceinline__ unsigned short f2bf(float f) {
    __hip_bfloat16 h = __float2bfloat16(f);
    return *reinterpret_cast<unsigned short*>(&h);
}

__global__ __launch_bounds__(256, 4) void pkl_kernel(
        const float* __restrict__ logits,
        const float* __restrict__ M,
        float* __restrict__ out) {
    __shared__ __hip_bfloat16 m_lds[CC * PST];      // M row-major [c][d] (B as N x K)
    __shared__ __hip_bfloat16 p_lds[ROWS * PST];    // block-shared log-softmax rows (bf16)

    const int tid  = threadIdx.x;
    const int lane = tid & 63;
    const int w    = tid >> 6;      // wave 0..3
    const int quad = lane >> 4;     // 0..3
    const int nlo  = lane & 15;     // 0..15

    const int b  = blockIdx.x >> 5;           // 32 blocks per batch row
    const int s0 = (blockIdx.x & 31) * 128;   // block's first position

    // ---- stage M -> bf16 LDS (coalesced) ----
    for (int j = 0; j < 16; ++j) {
        int idx = j * 256 + tid;               // 0..4095
        m_lds[(idx >> 6) * PST + (idx & 63)] = __float2bfloat16(M[idx]);
    }

    // ---- phase 1: float4 loads, softmax with 16-lane trees, 4 rows/wave/iter ----
    const float LOG2E = 1.4426950408889634f, LN2 = 0.6931471805599453f;
    for (int j = 0; j < 9; ++j) {
        int lr = j * 16 + w * 4 + quad;        // local row 0..128 (interleaved across waves)
        if (lr <= 128) {
            int grow = s0 + lr; if (grow > SS - 1) grow = SS - 1;
            const float4 x = *reinterpret_cast<const float4*>(
                logits + ((size_t)b * SS + grow) * CC + nlo * 4);
            float mx = fmaxf(fmaxf(x.x, x.y), fmaxf(x.z, x.w));
            #pragma unroll
            for (int o = 8; o > 0; o >>= 1) mx = fmaxf(mx, __shfl_xor(mx, o));
            float sm = exp2f((x.x - mx) * LOG2E) + exp2f((x.y - mx) * LOG2E)
                     + exp2f((x.z - mx) * LOG2E) + exp2f((x.w - mx) * LOG2E);
            #pragma unroll
            for (int o = 8; o > 0; o >>= 1) sm += __shfl_xor(sm, o);
            float lse = mx + log2f(sm) * LN2;  // logsumexp; p_i = x_i - lse
            ushort4 pk;
            pk.x = f2bf(x.x - lse); pk.y = f2bf(x.y - lse);
            pk.z = f2bf(x.z - lse); pk.w = f2bf(x.w - lse);
            *reinterpret_cast<ushort4*>(
                reinterpret_cast<unsigned short*>(p_lds) + lr * PST + nlo * 4) = pk;
        }
    }
    __syncthreads();

    // ---- phase 2: V[i][c] = sum_d P[w*32+1+i][d] * M[c][d]  via MFMA 16x16x32 ----
    // A[m=lane&15][k=quad*8+j] -> p row (w*32 + 1 + mt*16 + nlo), 8 contiguous bf16
    // B[n=lane&15][k=quad*8+j] -> M row (nt*16 + nlo), 8 contiguous bf16
    floatx4 acc[2][4];
    #pragma unroll
    for (int mt = 0; mt < 2; ++mt)
        #pragma unroll
        for (int nt = 0; nt < 4; ++nt)
            acc[mt][nt] = (floatx4){0.f, 0.f, 0.f, 0.f};

    #pragma unroll
    for (int kt = 0; kt < 2; ++kt) {
        const int koff = kt * 32 + quad * 8;
        short8 bfrag[4];
        #pragma unroll
        for (int nt = 0; nt < 4; ++nt)
            bfrag[nt] = *reinterpret_cast<const short8*>(
                reinterpret_cast<const short*>(m_lds) + (nt * 16 + nlo) * PST + koff);
        #pragma unroll
        for (int mt = 0; mt < 2; ++mt) {
            short8 afrag = *reinterpret_cast<const short8*>(
                reinterpret_cast<const short*>(p_lds) + (w * 32 + 1 + mt * 16 + nlo) * PST + koff);
            #pragma unroll
            for (int nt = 0; nt < 4; ++nt)
                acc[mt][nt] = __builtin_amdgcn_mfma_f32_16x16x32_bf16(
                    afrag, bfrag[nt], acc[mt][nt], 0, 0, 0);
        }
    }

    // ---- phase 3: r[t] = dot(p_t, V) straight from accumulators ----
    // C/D layout: c = nt*16 + nlo, V-row i = mt*16 + quad*4 + r  (t = s0 + w*32 + i)
    const size_t outbase = (size_t)b * (SS - 1);
    #pragma unroll
    for (int mt = 0; mt < 2; ++mt)
        #pragma unroll
        for (int r = 0; r < 4; ++r) {
            const int lrow = w * 32 + mt * 16 + quad * 4 + r;   // p_t local row
            float s = 0.f;
            #pragma unroll
            for (int nt = 0; nt < 4; ++nt)
                s += __bfloat162float(p_lds[lrow * PST + nt * 16 + nlo]) * acc[mt][nt][r];
            #pragma unroll
            for (int o = 8; o > 0; o >>= 1) s += __shfl_xor(s, o);
            if (nlo == 0) {
                int t = s0 + lrow;
                if (t <= SS - 2) out[outbase + t] = s;
            }
        }
}

extern "C" void kernel_launch(void* const* d_in, const int* in_sizes, int n_in,
                              void* d_out, int out_size, void* d_ws, size_t ws_size,
                              hipStream_t stream) {
    const float* logits = (const float*)d_in[0];   // [128, 4096, 64] fp32
    const float* M      = (const float*)d_in[1];   // [64, 64] fp32
    float* out          = (float*)d_out;           // [128, 4095] fp32

    dim3 grid(128 * 32), block(256);               // 128 positions per block
    hipLaunchKernelGGL(pkl_kernel, grid, block, 0, stream, logits, M, out);
}

// Round 3
// 192.701 us; speedup vs baseline: 1.9750x; 1.0180x over previous
//
#include <hip/hip_runtime.h>
#include <hip/hip_bf16.h>

// Problem: B=128, S=4096, C=64.  r[b,t] = p_t . (M p_{t+1}),  p = log_softmax(logits)
#define SS 4096
#define CC 64
#define PST 72           // padded LDS row stride in bf16 elems (144 B: 16B-aligned rows)
#define ROWS 129         // 128 positions per block + 1 overlap row

typedef __attribute__((ext_vector_type(8))) short short8;
typedef __attribute__((ext_vector_type(4))) float floatx4;

static __device__ __forceinline__ unsigned short f2bf(float f) {
    __hip_bfloat16 h = __float2bfloat16(f);
    return *reinterpret_cast<unsigned short*>(&h);
}

__global__ __launch_bounds__(256, 4) void pkl_kernel(
        const float* __restrict__ logits,
        const float* __restrict__ M,
        float* __restrict__ out) {
    __shared__ __hip_bfloat16 m_lds[CC * PST];      // M row-major [c][d] (B as N x K)
    __shared__ __hip_bfloat16 p_lds[ROWS * PST];    // block-shared log-softmax rows (bf16)

    const int tid  = threadIdx.x;
    const int lane = tid & 63;
    const int w    = tid >> 6;      // wave 0..3
    const int quad = lane >> 4;     // 0..3
    const int nlo  = lane & 15;     // 0..15

    const int b  = blockIdx.x >> 5;           // 32 blocks per batch row
    const int s0 = (blockIdx.x & 31) * 128;   // block's first position

    // ---- phase 1a: issue ALL 9 logits loads up front (independent, deep in flight) ----
    float4 x[9];
    #pragma unroll
    for (int j = 0; j < 9; ++j) {
        int lr = j * 16 + w * 4 + quad;        // local row
        int l  = lr > 128 ? 128 : lr;          // j=8 extra lanes re-load the overlap row (broadcast)
        int grow = s0 + l; if (grow > SS - 1) grow = SS - 1;
        x[j] = *reinterpret_cast<const float4*>(
            logits + ((size_t)b * SS + grow) * CC + nlo * 4);
    }

    // ---- stage M -> bf16 LDS (issues after logits loads; M is L2-resident) ----
    #pragma unroll 4
    for (int j = 0; j < 16; ++j) {
        int idx = j * 256 + tid;               // 0..4095
        m_lds[(idx >> 6) * PST + (idx & 63)] = __float2bfloat16(M[idx]);
    }

    // ---- phase 1b: softmax with 16-lane trees, 9 independent chains interleave ----
    const float LOG2E = 1.4426950408889634f, LN2 = 0.6931471805599453f;
    #pragma unroll
    for (int j = 0; j < 9; ++j) {
        int lr = j * 16 + w * 4 + quad;
        float mx = fmaxf(fmaxf(x[j].x, x[j].y), fmaxf(x[j].z, x[j].w));
        #pragma unroll
        for (int o = 8; o > 0; o >>= 1) mx = fmaxf(mx, __shfl_xor(mx, o));
        float sm = exp2f((x[j].x - mx) * LOG2E) + exp2f((x[j].y - mx) * LOG2E)
                 + exp2f((x[j].z - mx) * LOG2E) + exp2f((x[j].w - mx) * LOG2E);
        #pragma unroll
        for (int o = 8; o > 0; o >>= 1) sm += __shfl_xor(sm, o);
        float lse = mx + log2f(sm) * LN2;      // logsumexp; p_i = x_i - lse
        if (lr <= 128) {
            ushort4 pk;
            pk.x = f2bf(x[j].x - lse); pk.y = f2bf(x[j].y - lse);
            pk.z = f2bf(x[j].z - lse); pk.w = f2bf(x[j].w - lse);
            *reinterpret_cast<ushort4*>(
                reinterpret_cast<unsigned short*>(p_lds) + lr * PST + nlo * 4) = pk;
        }
    }
    __syncthreads();

    // ---- phase 2: V[i][c] = sum_d P[w*32+1+i][d] * M[c][d]  via MFMA 16x16x32 ----
    // A[m=lane&15][k=quad*8+j] -> p row (w*32 + 1 + mt*16 + nlo), 8 contiguous bf16
    // B[n=lane&15][k=quad*8+j] -> M row (nt*16 + nlo), 8 contiguous bf16
    floatx4 acc[2][4];
    #pragma unroll
    for (int mt = 0; mt < 2; ++mt)
        #pragma unroll
        for (int nt = 0; nt < 4; ++nt)
            acc[mt][nt] = (floatx4){0.f, 0.f, 0.f, 0.f};

    #pragma unroll
    for (int kt = 0; kt < 2; ++kt) {
        const int koff = kt * 32 + quad * 8;
        short8 bfrag[4];
        #pragma unroll
        for (int nt = 0; nt < 4; ++nt)
            bfrag[nt] = *reinterpret_cast<const short8*>(
                reinterpret_cast<const short*>(m_lds) + (nt * 16 + nlo) * PST + koff);
        #pragma unroll
        for (int mt = 0; mt < 2; ++mt) {
            short8 afrag = *reinterpret_cast<const short8*>(
                reinterpret_cast<const short*>(p_lds) + (w * 32 + 1 + mt * 16 + nlo) * PST + koff);
            #pragma unroll
            for (int nt = 0; nt < 4; ++nt)
                acc[mt][nt] = __builtin_amdgcn_mfma_f32_16x16x32_bf16(
                    afrag, bfrag[nt], acc[mt][nt], 0, 0, 0);
        }
    }

    // ---- phase 3: r[t] = dot(p_t, V) straight from accumulators ----
    // C/D layout: c = nt*16 + nlo, V-row i = mt*16 + quad*4 + r  (t = s0 + w*32 + i)
    const size_t outbase = (size_t)b * (SS - 1);
    #pragma unroll
    for (int mt = 0; mt < 2; ++mt)
        #pragma unroll
        for (int r = 0; r < 4; ++r) {
            const int lrow = w * 32 + mt * 16 + quad * 4 + r;   // p_t local row
            float s = 0.f;
            #pragma unroll
            for (int nt = 0; nt < 4; ++nt)
                s += __bfloat162float(p_lds[lrow * PST + nt * 16 + nlo]) * acc[mt][nt][r];
            #pragma unroll
            for (int o = 8; o > 0; o >>= 1) s += __shfl_xor(s, o);
            if (nlo == 0) {
                int t = s0 + lrow;
                if (t <= SS - 2) out[outbase + t] = s;
            }
        }
}

extern "C" void kernel_launch(void* const* d_in, const int* in_sizes, int n_in,
                              void* d_out, int out_size, void* d_ws, size_t ws_size,
                              hipStream_t stream) {
    const float* logits = (const float*)d_in[0];   // [128, 4096, 64] fp32
    const float* M      = (const float*)d_in[1];   // [64, 64] fp32
    float* out          = (float*)d_out;           // [128, 4095] fp32

    dim3 grid(128 * 32), block(256);               // 128 positions per block
    hipLaunchKernelGGL(pkl_kernel, grid, block, 0, stream, logits, M, out);
}

// Round 4
// 188.788 us; speedup vs baseline: 2.0159x; 1.0207x over previous
//
#include <hip/hip_runtime.h>
#include <hip/hip_bf16.h>

// Problem: B=128, S=4096, C=64.  r[b,t] = p_t . (M p_{t+1}),  p = log_softmax(logits)
// Class storage is sigma-permuted everywhere in LDS: class c = 16j+4q+k  (j,q,k in 0..3,
// per phase-1 lane layout) is stored at c' = 16q+4k+j == 4*(c&15) + (c>>4).
// MFMA over k is invariant to a k-permutation applied to BOTH operands, so P and M
// are both stored in sigma order; phase 3 then reads each lane's 4 needed classes
// {16nt+nlo} as ONE contiguous ds_read_b64 at c' = 4*nlo.
#define SS 4096
#define CC 64
#define PST 72            // LDS row stride in bf16 (144 B = 9 x 16 B, keeps b128 alignment)
#define NROWS 129

typedef __attribute__((ext_vector_type(8))) short short8;
typedef __attribute__((ext_vector_type(4))) float floatx4;

static __device__ __forceinline__ unsigned short f2bf(float f) {
    __hip_bfloat16 h = __float2bfloat16(f);
    return *reinterpret_cast<unsigned short*>(&h);
}
static __device__ __forceinline__ float bf2f(unsigned short u) {
    __hip_bfloat16 h; *reinterpret_cast<unsigned short*>(&h) = u;
    return __bfloat162float(h);
}
static __device__ __forceinline__ float f4c(const float4& v, int k) {
    switch (k & 3) { case 0: return v.x; case 1: return v.y; case 2: return v.z; default: return v.w; }
}

// DPP cross-lane reductions on the VALU pipe (no LDS traffic).
#define DPP_QX1 0xB1   // quad_perm [1,0,3,2]  == xor 1
#define DPP_QX2 0x4E   // quad_perm [2,3,0,1]  == xor 2
#define DPP_HM  0x141  // row_half_mirror (xor 7 within 8)
#define DPP_RM  0x140  // row_mirror      (xor 15 within 16)
template<int CTRL>
static __device__ __forceinline__ float dpp_fadd(float v) {
    int p = __builtin_amdgcn_update_dpp(0, __float_as_int(v), CTRL, 0xf, 0xf, true);
    return v + __int_as_float(p);
}
template<int CTRL>
static __device__ __forceinline__ float dpp_fmax(float v) {
    int p = __builtin_amdgcn_update_dpp(0, __float_as_int(v), CTRL, 0xf, 0xf, true);
    return fmaxf(v, __int_as_float(p));
}

__global__ __launch_bounds__(256, 4) void pkl_kernel(
        const float* __restrict__ logits,
        const float* __restrict__ M,
        float* __restrict__ out) {
    __shared__ __hip_bfloat16 mt_lds[CC * PST];      // M rows, sigma-permuted cols
    __shared__ __hip_bfloat16 pt_lds[NROWS * PST];   // log-softmax rows, sigma-permuted cols

    const int tid  = threadIdx.x;
    const int lane = tid & 63;
    const int w    = tid >> 6;       // wave 0..3
    const int quad = lane >> 4;      // 0..3
    const int nlo  = lane & 15;      // 0..15
    const int rq   = lane >> 2;      // phase-1: row-within-wave 0..15
    const int q    = lane & 3;       // phase-1: quarter of row (4 lanes per row)

    const int b  = blockIdx.x >> 5;            // 32 blocks per batch row
    const int s0 = (blockIdx.x & 31) * 128;    // block's first position
    const float* lg = logits + (size_t)b * SS * CC;
    const float LOG2E = 1.4426950408889634f, LN2 = 0.6931471805599453f;

    // ---- phase 1a: all global loads up front. 4 lanes/row, 16 floats/lane,
    //      fully coalesced (chunk ch = 4j+q -> consecutive lanes consecutive 16 B) ----
    float4 xa[2][4];
    #pragma unroll
    for (int i = 0; i < 2; ++i) {
        const int lr = i * 64 + w * 16 + rq;                 // 0..127, all valid
        const float* rp = lg + (size_t)(s0 + lr) * CC;
        #pragma unroll
        for (int j = 0; j < 4; ++j)
            xa[i][j] = *reinterpret_cast<const float4*>(rp + (j * 4 + q) * 4);
    }

    // ---- stage Mt (sigma cols): Mt[c][16q+4k+j] = M[c][16j+4q+k]; M is L2-resident ----
    const int mc = tid >> 2;                                 // 0..63
    float mv[16];
    #pragma unroll
    for (int k = 0; k < 4; ++k)
        #pragma unroll
        for (int j = 0; j < 4; ++j)
            mv[4 * k + j] = M[mc * CC + 16 * j + 4 * q + k];
    {
        short8 g0, g1;
        #pragma unroll
        for (int o = 0; o < 8; ++o) { g0[o] = (short)f2bf(mv[o]); g1[o] = (short)f2bf(mv[o + 8]); }
        short* mp = reinterpret_cast<short*>(mt_lds) + mc * PST + 16 * q;
        *reinterpret_cast<short8*>(mp) = g0;
        *reinterpret_cast<short8*>(mp + 8) = g1;
    }

    // ---- phase 1b: softmax, 16 in-lane values + 2 DPP steps over the 4-lane quad ----
    #pragma unroll
    for (int i = 0; i < 2; ++i) {
        const int lr = i * 64 + w * 16 + rq;
        float mx = f4c(xa[i][0], 0);
        #pragma unroll
        for (int j = 0; j < 4; ++j)
            #pragma unroll
            for (int k = 0; k < 4; ++k)
                mx = fmaxf(mx, f4c(xa[i][j], k));
        mx = dpp_fmax<DPP_QX1>(mx); mx = dpp_fmax<DPP_QX2>(mx);
        float sm = 0.f;
        #pragma unroll
        for (int j = 0; j < 4; ++j)
            #pragma unroll
            for (int k = 0; k < 4; ++k)
                sm += exp2f((f4c(xa[i][j], k) - mx) * LOG2E);
        sm = dpp_fadd<DPP_QX1>(sm); sm = dpp_fadd<DPP_QX2>(sm);
        const float lse = mx + log2f(sm) * LN2;
        // sigma write: lane's 16 values are contiguous at c' = 16q + (4k+j)
        short8 h0, h1;
        #pragma unroll
        for (int o = 0; o < 8; ++o) {
            h0[o] = (short)f2bf(f4c(xa[i][o & 3], o >> 2) - lse);          // o   = 4k+j
            h1[o] = (short)f2bf(f4c(xa[i][(o + 8) & 3], (o + 8) >> 2) - lse);
        }
        short* pp = reinterpret_cast<short*>(pt_lds) + lr * PST + 16 * q;
        *reinterpret_cast<short8*>(pp) = h0;
        *reinterpret_cast<short8*>(pp + 8) = h1;
    }

    // ---- overlap row 128 (= next block's row 0), done by lanes 0..3 of wave 0 ----
    if (tid < 4) {                                           // q == tid, quad 0
        const int grow = min(s0 + 128, SS - 1);              // clamp only matters for last block
        const float* rp = lg + (size_t)grow * CC;
        float4 y[4];
        #pragma unroll
        for (int j = 0; j < 4; ++j)
            y[j] = *reinterpret_cast<const float4*>(rp + (j * 4 + tid) * 4);
        float mx = f4c(y[0], 0);
        #pragma unroll
        for (int j = 0; j < 4; ++j)
            #pragma unroll
            for (int k = 0; k < 4; ++k)
                mx = fmaxf(mx, f4c(y[j], k));
        mx = dpp_fmax<DPP_QX1>(mx); mx = dpp_fmax<DPP_QX2>(mx);
        float sm = 0.f;
        #pragma unroll
        for (int j = 0; j < 4; ++j)
            #pragma unroll
            for (int k = 0; k < 4; ++k)
                sm += exp2f((f4c(y[j], k) - mx) * LOG2E);
        sm = dpp_fadd<DPP_QX1>(sm); sm = dpp_fadd<DPP_QX2>(sm);
        const float lse = mx + log2f(sm) * LN2;
        short8 h0, h1;
        #pragma unroll
        for (int o = 0; o < 8; ++o) {
            h0[o] = (short)f2bf(f4c(y[o & 3], o >> 2) - lse);
            h1[o] = (short)f2bf(f4c(y[(o + 8) & 3], (o + 8) >> 2) - lse);
        }
        short* pp = reinterpret_cast<short*>(pt_lds) + 128 * PST + 16 * tid;
        *reinterpret_cast<short8*>(pp) = h0;
        *reinterpret_cast<short8*>(pp + 8) = h1;
    }
    __syncthreads();

    // ---- phase 2: V[i][c] = sum_d P[w*32+1+i][d] * M[c][d], MFMA 16x16x32 (sigma-k) ----
    floatx4 acc[2][4];
    #pragma unroll
    for (int mt = 0; mt < 2; ++mt)
        #pragma unroll
        for (int nt = 0; nt < 4; ++nt)
            acc[mt][nt] = (floatx4){0.f, 0.f, 0.f, 0.f};

    #pragma unroll
    for (int kt = 0; kt < 2; ++kt) {
        const int koff = kt * 32 + quad * 8;
        short8 bfrag[4];
        #pragma unroll
        for (int nt = 0; nt < 4; ++nt)
            bfrag[nt] = *reinterpret_cast<const short8*>(
                reinterpret_cast<const short*>(mt_lds) + (nt * 16 + nlo) * PST + koff);
        #pragma unroll
        for (int mt = 0; mt < 2; ++mt) {
            short8 afrag = *reinterpret_cast<const short8*>(
                reinterpret_cast<const short*>(pt_lds) + (w * 32 + 1 + mt * 16 + nlo) * PST + koff);
            #pragma unroll
            for (int nt = 0; nt < 4; ++nt)
                acc[mt][nt] = __builtin_amdgcn_mfma_f32_16x16x32_bf16(
                    afrag, bfrag[nt], acc[mt][nt], 0, 0, 0);
        }
    }

    // ---- phase 3: r[t] = dot(p_t, V[t+1]).  acc[mt][nt][r] = V[w*32+1+mt*16+quad*4+r][16nt+nlo].
    //      Lane's 4 p-classes {16nt+nlo} sit contiguous at sigma c' = 4*nlo -> one ds_read_b64. ----
    const size_t outbase = (size_t)b * (SS - 1);
    #pragma unroll
    for (int mt = 0; mt < 2; ++mt)
        #pragma unroll
        for (int r = 0; r < 4; ++r) {
            const int lrow = w * 32 + mt * 16 + quad * 4 + r;        // t local, 0..127
            ushort4 pd = *reinterpret_cast<const ushort4*>(
                reinterpret_cast<const unsigned short*>(pt_lds) + lrow * PST + 4 * nlo);
            float s = bf2f(pd.x) * acc[mt][0][r] + bf2f(pd.y) * acc[mt][1][r]
                    + bf2f(pd.z) * acc[mt][2][r] + bf2f(pd.w) * acc[mt][3][r];
            s = dpp_fadd<DPP_QX1>(s); s = dpp_fadd<DPP_QX2>(s);
            s = dpp_fadd<DPP_HM>(s);  s = dpp_fadd<DPP_RM>(s);       // sum over 16-lane row
            if (nlo == 0) {
                const int t = s0 + lrow;
                if (t <= SS - 2) out[outbase + t] = s;
            }
        }
}

extern "C" void kernel_launch(void* const* d_in, const int* in_sizes, int n_in,
                              void* d_out, int out_size, void* d_ws, size_t ws_size,
                              hipStream_t stream) {
    const float* logits = (const float*)d_in[0];   // [128, 4096, 64] fp32
    const float* M      = (const float*)d_in[1];   // [64, 64] fp32
    float* out          = (float*)d_out;           // [128, 4095] fp32

    dim3 grid(128 * 32), block(256);               // 128 outputs per block
    hipLaunchKernelGGL(pkl_kernel, grid, block, 0, stream, logits, M, out);
}